// Round 3
// baseline (151.330 us; speedup 1.0000x reference)
//
#include <hip/hip_runtime.h>
#include <hip/hip_bf16.h>
#include <cstdint>

#define B_   2
#define L_   2048
#define DIM_ 1024
#define H_   16
#define HD_  64
#define M_   (B_ * L_)    // 4096
#define N3_  (3 * DIM_)   // 3072

typedef unsigned short ushort_t;
typedef __bf16 bf16x8 __attribute__((ext_vector_type(8)));
typedef float  f32x4  __attribute__((ext_vector_type(4)));
typedef float  f32x16 __attribute__((ext_vector_type(16)));
typedef unsigned u32x2_t __attribute__((ext_vector_type(2)));

// native cast -> compiler emits v_cvt_pk_bf16_f32 for adjacent pairs (RTNE)
__device__ __forceinline__ unsigned short f2b(float f) {
  return __builtin_bit_cast(unsigned short, (__bf16)f);
}
__device__ __forceinline__ float b2f(unsigned short s) {
  unsigned u = ((unsigned)s) << 16;
  return __builtin_bit_cast(float, u);
}
__device__ __forceinline__ float fmax3(float a, float b, float c) {
  return fmaxf(fmaxf(a, b), c);   // fuses to v_max3_f32
}

// {a,b} -> a' = [a_lo | b_lo], b' = [a_hi | b_hi]  (lane halves)
__device__ __forceinline__ void plswap(unsigned &a, unsigned &b) {
#if defined(__has_builtin) && __has_builtin(__builtin_amdgcn_permlane32_swap)
  u32x2_t r = __builtin_amdgcn_permlane32_swap(a, b, false, false);
  a = r[0]; b = r[1];
#else
  unsigned sa = (unsigned)__shfl_xor((int)a, 32);
  unsigned sb = (unsigned)__shfl_xor((int)b, 32);
  bool hi = (threadIdx.x & 32) != 0;
  unsigned na = hi ? sb : a;
  unsigned nb = hi ? b : sa;
  a = na; b = nb;
#endif
}

typedef const __attribute__((address_space(1))) void* as1cp;
typedef __attribute__((address_space(3))) void* as3p;
__device__ __forceinline__ void gload_lds16(const void* g, void* l) {
  __builtin_amdgcn_global_load_lds((as1cp)g, (as3p)l, 16, 0, 0);
}

// ---------------- elementwise f32 -> bf16 ----------------
__global__ __launch_bounds__(256)
void conv_bf16(const float* __restrict__ in, ushort_t* __restrict__ out, int n4) {
  int i = blockIdx.x * 256 + threadIdx.x;
  if (i >= n4) return;
  float4 v = *(const float4*)&in[(size_t)i * 4];
  ushort4 o;
  o.x = f2b(v.x); o.y = f2b(v.y); o.z = f2b(v.z); o.w = f2b(v.w);
  *(ushort4*)&out[(size_t)i * 4] = o;
}

// ---------------- f32 [R][C] -> bf16 [C][R] transpose ----------------
__global__ __launch_bounds__(256)
void transpose_conv(const float* __restrict__ in, ushort_t* __restrict__ out,
                    int R, int C) {
  __shared__ float tile[64][65];
  const int t = threadIdx.x;
  const int r0 = blockIdx.y * 64, c0 = blockIdx.x * 64;
#pragma unroll
  for (int p = 0; p < 4; ++p) {
    int r = (t >> 4) + p * 16;
    int c = (t & 15) * 4;
    float4 v = *(const float4*)&in[(size_t)(r0 + r) * C + (c0 + c)];
    tile[r][c + 0] = v.x; tile[r][c + 1] = v.y;
    tile[r][c + 2] = v.z; tile[r][c + 3] = v.w;
  }
  __syncthreads();
#pragma unroll
  for (int p = 0; p < 4; ++p) {
    int cc = (t >> 4) + p * 16;
    int r  = (t & 15) * 4;
    ushort4 o;
    o.x = f2b(tile[r + 0][cc]); o.y = f2b(tile[r + 1][cc]);
    o.z = f2b(tile[r + 2][cc]); o.w = f2b(tile[r + 3][cc]);
    *(ushort4*)&out[(size_t)(c0 + cc) * R + (r0 + r)] = o;
  }
}

// ---------------- rope cos/sin table [L][32] ----------------
__global__ __launch_bounds__(256)
void rope_tab(float* __restrict__ cosT, float* __restrict__ sinT) {
  int idx = blockIdx.x * 256 + threadIdx.x;   // 65536 = 2048*32
  int l = idx >> 5, d = idx & 31;
  float inv_freq = expf(-((float)(2 * d) / 64.f) * logf(10000.f));
  float ang = (float)l * inv_freq;
  cosT[idx] = cosf(ang);
  sinT[idx] = sinf(ang);
}

// ---------------- GEMM: A[M][K] bf16 @ BT[N][K] bf16 ----------------
// 128x128 tile, BK=32, 4 waves (2x2), 16x16x32 MFMA, global_load_lds staging.
// MODE 0: QKV gemm -> q,k cols [0,2048) to Cqk[row][ldc]; V cols [2048,3072)
//         transposed to vt[b][d][l].  MODE 1: f32 out + bias.
template <int MODE>
__global__ __launch_bounds__(256)
void gemm_bt(const ushort_t* __restrict__ A, const ushort_t* __restrict__ BT,
             void* __restrict__ Cout, ushort_t* __restrict__ vtout,
             const float* __restrict__ bias, int M, int N, int K, int ldc) {
  __shared__ ushort_t As[128 * 32];
  __shared__ ushort_t Bs[128 * 32];
  const int lane = threadIdx.x & 63;
  const int wid  = threadIdx.x >> 6;
  const int wm = wid >> 1, wn = wid & 1;
  const int m0 = blockIdx.y * 128, n0 = blockIdx.x * 128;
  const int ro = lane & 15, kg = lane >> 4;

  f32x4 acc[4][4] = {};

  for (int k0 = 0; k0 < K; k0 += 32) {
    const int cb = wid * 128;
#pragma unroll
    for (int j = 0; j < 2; ++j) {
      int c = cb + j * 64 + lane;
      gload_lds16(A + (size_t)(m0 + (c >> 2)) * K + k0 + (c & 3) * 8,
                  &As[(cb + j * 64) * 8]);
    }
#pragma unroll
    for (int j = 0; j < 2; ++j) {
      int c = cb + j * 64 + lane;
      gload_lds16(BT + (size_t)(n0 + (c >> 2)) * K + k0 + (c & 3) * 8,
                  &Bs[(cb + j * 64) * 8]);
    }
    __syncthreads();
    bf16x8 af[4], bfr[4];
#pragma unroll
    for (int i = 0; i < 4; ++i)
      af[i] = *(const bf16x8*)&As[(wm * 64 + i * 16 + ro) * 32 + kg * 8];
#pragma unroll
    for (int i = 0; i < 4; ++i)
      bfr[i] = *(const bf16x8*)&Bs[(wn * 64 + i * 16 + ro) * 32 + kg * 8];
#pragma unroll
    for (int i = 0; i < 4; ++i)
#pragma unroll
      for (int j = 0; j < 4; ++j)
        acc[i][j] = __builtin_amdgcn_mfma_f32_16x16x32_bf16(af[i], bfr[j],
                                                            acc[i][j], 0, 0, 0);
    __syncthreads();
  }

  if (MODE == 0) {
    if (n0 < 2048) {
#pragma unroll
      for (int i = 0; i < 4; ++i)
#pragma unroll
        for (int r = 0; r < 4; ++r) {
          int row = m0 + wm * 64 + i * 16 + kg * 4 + r;
#pragma unroll
          for (int j = 0; j < 4; ++j) {
            int col = n0 + wn * 64 + j * 16 + ro;
            ((ushort_t*)Cout)[(size_t)row * ldc + col] = f2b(acc[i][j][r]);
          }
        }
    } else {
      // V columns -> vt[b][dg][l], 4 consecutive l per lane packed
#pragma unroll
      for (int i = 0; i < 4; ++i) {
        int rowb = m0 + wm * 64 + i * 16 + kg * 4;
        int bb = rowb >> 11, l = rowb & (L_ - 1);
#pragma unroll
        for (int j = 0; j < 4; ++j) {
          int dg = (n0 - 2048) + wn * 64 + j * 16 + ro;
          ushort4 o;
          o.x = f2b(acc[i][j][0]); o.y = f2b(acc[i][j][1]);
          o.z = f2b(acc[i][j][2]); o.w = f2b(acc[i][j][3]);
          *(ushort4*)&vtout[((size_t)bb * DIM_ + dg) * L_ + l] = o;
        }
      }
    }
  } else {
#pragma unroll
    for (int i = 0; i < 4; ++i)
#pragma unroll
      for (int r = 0; r < 4; ++r) {
        int row = m0 + wm * 64 + i * 16 + kg * 4 + r;
#pragma unroll
        for (int j = 0; j < 4; ++j) {
          int col = n0 + wn * 64 + j * 16 + ro;
          ((float*)Cout)[(size_t)row * ldc + col] = acc[i][j][r] + bias[col];
        }
      }
  }
}

// ---------------- fused per-head RMSNorm + RoPE on q,k (in place) ----------------
// qk layout [token][2048]: q cols [0,1024), k cols [1024,2048).
// Q additionally prescaled by 0.125*log2(e) so attention uses exp2 directly.
__global__ __launch_bounds__(256)
void rmsrope(ushort_t* __restrict__ qk, const float* __restrict__ qs,
             const float* __restrict__ ks, const float* __restrict__ cosT,
             const float* __restrict__ sinT) {
  const int t = blockIdx.x;          // token 0..4095
  const int l = t & (L_ - 1);
  const int j = threadIdx.x & 15;    // 16 threads per head
  const int h = threadIdx.x >> 4;
  const int dd = (j & 7) * 4;
  float4 cv = *(const float4*)&cosT[l * 32 + dd];
  float4 sv = *(const float4*)&sinT[l * 32 + dd];
  const float sgn = (j < 8) ? -1.f : 1.f;
#pragma unroll
  for (int ic = 0; ic < 2; ++ic) {
    const float qsc = (ic == 0) ? 0.125f * 1.44269504088896341f : 1.f;
    ushort_t* base = qk + (size_t)t * 2048 + ic * DIM_ + h * HD_ + j * 4;
    ushort4 raw = *(const ushort4*)base;
    float x0 = b2f(raw.x), x1 = b2f(raw.y), x2 = b2f(raw.z), x3 = b2f(raw.w);
    float ss = x0 * x0 + x1 * x1 + x2 * x2 + x3 * x3;
    ss += __shfl_xor(ss, 1); ss += __shfl_xor(ss, 2);
    ss += __shfl_xor(ss, 4); ss += __shfl_xor(ss, 8);
    float inv = rsqrtf(ss * (1.f / 64.f) + 1e-6f);
    const float* scp = (ic == 0 ? qs : ks) + j * 4;
    float4 sc = *(const float4*)scp;
    x0 *= inv * sc.x; x1 *= inv * sc.y; x2 *= inv * sc.z; x3 *= inv * sc.w;
    float y0 = __shfl_xor(x0, 8), y1 = __shfl_xor(x1, 8);
    float y2 = __shfl_xor(x2, 8), y3 = __shfl_xor(x3, 8);
    ushort4 o;
    o.x = f2b((x0 * cv.x + sgn * y0 * sv.x) * qsc);
    o.y = f2b((x1 * cv.y + sgn * y1 * sv.y) * qsc);
    o.z = f2b((x2 * cv.z + sgn * y2 * sv.z) * qsc);
    o.w = f2b((x3 * cv.w + sgn * y3 * sv.w) * qsc);
    *(ushort4*)base = o;
  }
}

// ---------------- flash attention, 32x32 MFMA, P-in-register ----------------
// grid (L/128, H, B), 256 thr = 4 waves, wave owns 32 q-rows.
// Swapped QK^T via mfma_f32_32x32x16: D[k][q], col=lane&31=q -> softmax
// bookkeeping is lane-uniform (alpha, 1/l in-lane, no shfl redistribution).
// P redistributed to PV B-fragments in-register via cvt_pk + permlane32_swap
// (T12): no P LDS round-trip. O^T[d][q] accumulated via mfma(Vfrag, Pfrag).
// K/V XOR-swizzled LDS, double-buffered global_load_lds staging, 1 barrier/tile.
__global__ __launch_bounds__(256)
void flash_attn(const ushort_t* __restrict__ qk, const ushort_t* __restrict__ vt,
                ushort_t* __restrict__ O) {
  const int qt = blockIdx.x, h = blockIdx.y, b = blockIdx.z;
  const int lane = threadIdx.x & 63, wid = threadIdx.x >> 6;
  const int lq = lane & 31;          // q (QK) / d' (PV A) / col index
  const int hi = lane >> 5;          // lane-half: k-slice half selector
  const int q0 = qt * 128;
  const size_t tok0 = (size_t)b * L_;
  const ushort_t* qb = qk + tok0 * 2048 + h * HD_;
  const ushort_t* kb = qb + DIM_;
  const ushort_t* vb = vt + ((size_t)b * DIM_ + h * HD_) * L_;

  __shared__ ushort_t Ks[2][4096];   // [kpos 64][d 64], 16B-chunk XOR swizzle
  __shared__ ushort_t Vs[2][4096];   // [d 64][kpos 64], same swizzle

  // staging: each thread 2x K + 2x V chunks, source pre-swizzled (rule 21)
  const int srow0 = wid * 16 + (lane >> 3);
  const int sch   = lane & 7;
  auto STAGE = [&](int bufi, int kt) {
#pragma unroll
    for (int j = 0; j < 2; ++j) {
      int row = srow0 + j * 8;
      int sc  = sch ^ (row & 7);
      gload_lds16(kb + (size_t)(kt * 64 + row) * 2048 + sc * 8,
                  &Ks[bufi][wid * 1024 + j * 512]);
      gload_lds16(vb + (size_t)row * L_ + kt * 64 + sc * 8,
                  &Vs[bufi][wid * 1024 + j * 512]);
    }
  };

  // Q fragments: B-operand of QK^T.  qf[s]: Q[q=lq][d = 16s + hi*8 + j]
  bf16x8 qf[4];
  {
    const ushort_t* gp = qb + (size_t)(q0 + wid * 32 + lq) * 2048;
#pragma unroll
    for (int s = 0; s < 4; ++s)
      qf[s] = *(const bf16x8*)(gp + s * 16 + hi * 8);
  }

  // swizzled chunk byte-offsets (ushort units), shared by K d-slices and V
  // k-slices: chunk = (2*idx + hi) ^ (lq & 7)
  int chs[4];
#pragma unroll
  for (int s = 0; s < 4; ++s) chs[s] = ((2 * s + hi) ^ (lq & 7)) * 8;

  f32x16 oaccT[2] = {};              // [dtile] D[row=d'][col=q=lq]
  float mrow = -1e30f, lrow = 0.f;   // per-lane: q = lq (half-sum in lrow)

  STAGE(0, 0);
  __syncthreads();

  auto TILE = [&](int bi, int kt) {
    if (kt + 1 < L_ / 64) STAGE(bi ^ 1, kt + 1);
    const ushort_t* kb0 = &Ks[bi][lq * 64];
    const ushort_t* vb0 = &Vs[bi][lq * 64];

    // S^T tiles: st[t] = K[ktile t rows] . Q^T  -> D[kpos][q]
    f32x16 st[2];
    __builtin_amdgcn_s_setprio(1);
#pragma unroll
    for (int t = 0; t < 2; ++t) {
      f32x16 z = {};
#pragma unroll
      for (int s = 0; s < 4; ++s) {
        bf16x8 kf = *(const bf16x8*)(kb0 + t * 2048 + chs[s]);
        z = __builtin_amdgcn_mfma_f32_32x32x16_bf16(kf, qf[s], z, 0, 0, 0);
      }
      st[t] = z;
    }
    __builtin_amdgcn_s_setprio(0);

    // row max: in-lane tree over 32 regs + cross-half
    float mx0, mx1, mx2, mx3;
    {
      float a0 = fmaxf(fmaxf(st[0][0], st[0][1]),  fmaxf(st[0][2], st[0][3]));
      float a1 = fmaxf(fmaxf(st[0][4], st[0][5]),  fmaxf(st[0][6], st[0][7]));
      float a2 = fmaxf(fmaxf(st[0][8], st[0][9]),  fmaxf(st[0][10], st[0][11]));
      float a3 = fmaxf(fmaxf(st[0][12], st[0][13]), fmaxf(st[0][14], st[0][15]));
      float b0 = fmaxf(fmaxf(st[1][0], st[1][1]),  fmaxf(st[1][2], st[1][3]));
      float b1 = fmaxf(fmaxf(st[1][4], st[1][5]),  fmaxf(st[1][6], st[1][7]));
      float b2 = fmaxf(fmaxf(st[1][8], st[1][9]),  fmaxf(st[1][10], st[1][11]));
      float b3 = fmaxf(fmaxf(st[1][12], st[1][13]), fmaxf(st[1][14], st[1][15]));
      mx0 = fmaxf(a0, b0); mx1 = fmaxf(a1, b1);
      mx2 = fmaxf(a2, b2); mx3 = fmaxf(a3, b3);
    }
    float pmw = fmaxf(fmax3(mx0, mx1, mx2), mx3);
    float pm  = fmaxf(pmw, __shfl_xor(pmw, 32));

    // defer-max: rescale only when some row's max grew by >8 (log2 domain;
    // P then bounded by 2^8, f32 accum has ample headroom)
    if (__any(pm > mrow + 8.f)) {
      float mn = fmaxf(mrow, pm);
      float alpha = __builtin_amdgcn_exp2f(mrow - mn);
      mrow = mn;
      lrow *= alpha;
#pragma unroll
      for (int dt = 0; dt < 2; ++dt)
#pragma unroll
        for (int r = 0; r < 16; ++r) oaccT[dt][r] *= alpha;
    }

    // P = exp2(S - m), packed bf16 pairs; partial row-sums for ILP
    unsigned pk[2][8];
    float rs0 = 0.f, rs1 = 0.f, rs2 = 0.f, rs3 = 0.f;
#pragma unroll
    for (int t = 0; t < 2; ++t)
#pragma unroll
      for (int p = 0; p < 8; ++p) {
        float e0 = __builtin_amdgcn_exp2f(st[t][2 * p]     - mrow);
        float e1 = __builtin_amdgcn_exp2f(st[t][2 * p + 1] - mrow);
        if ((p & 3) == 0) { rs0 += e0; rs1 += e1; }
        else if ((p & 3) == 1) { rs2 += e0; rs3 += e1; }
        else if ((p & 3) == 2) { rs0 += e0; rs1 += e1; }
        else { rs2 += e0; rs3 += e1; }
        pk[t][p] = (unsigned)f2b(e0) | ((unsigned)f2b(e1) << 16);
      }
    lrow += (rs0 + rs1) + (rs2 + rs3);

    // PV: redistribute P via permlane32_swap into B-fragments, then
    // oaccT[dt] += mfma(V^T-frag, P-frag).  8 MFMA, 8 V ds_reads.
    __builtin_amdgcn_s_setprio(1);
#pragma unroll
    for (int t = 0; t < 2; ++t)
#pragma unroll
      for (int blk = 0; blk < 2; ++blk) {
        unsigned w0 = pk[t][4 * blk + 0], w1 = pk[t][4 * blk + 1];
        unsigned w2 = pk[t][4 * blk + 2], w3 = pk[t][4 * blk + 3];
        plswap(w0, w2);   // -> {j0j1, j4j5}
        plswap(w1, w3);   // -> {j2j3, j6j7}
        uint4 bw; bw.x = w0; bw.y = w1; bw.z = w2; bw.w = w3;
        bf16x8 pf = __builtin_bit_cast(bf16x8, bw);
        const int sg = 2 * t + blk;
#pragma unroll
        for (int dt = 0; dt < 2; ++dt) {
          bf16x8 vf = *(const bf16x8*)(vb0 + dt * 2048 + chs[sg]);
          oaccT[dt] = __builtin_amdgcn_mfma_f32_32x32x16_bf16(vf, pf,
                                                              oaccT[dt], 0, 0, 0);
        }
      }
    __builtin_amdgcn_s_setprio(0);

    __syncthreads();   // drains vmcnt: stage(kt+1) complete; buffers safe
  };

  for (int kt = 0; kt < L_ / 64; kt += 2) {
    TILE(0, kt);
    TILE(1, kt + 1);
  }

  // epilogue: all lane-local (q = lq)
  lrow += __shfl_xor(lrow, 32);
  float linv = 1.f / lrow;
  ushort_t* obp = O + (size_t)(tok0 + q0 + wid * 32 + lq) * DIM_ + h * HD_;
#pragma unroll
  for (int dt = 0; dt < 2; ++dt)
#pragma unroll
    for (int g4 = 0; g4 < 4; ++g4) {
      int d0 = dt * 32 + g4 * 8 + hi * 4;
      ushort4 o4;
      o4.x = f2b(oaccT[dt][4 * g4 + 0] * linv);
      o4.y = f2b(oaccT[dt][4 * g4 + 1] * linv);
      o4.z = f2b(oaccT[dt][4 * g4 + 2] * linv);
      o4.w = f2b(oaccT[dt][4 * g4 + 3] * linv);
      *(ushort4*)(obp + d0) = o4;
    }
}

// ---------------- launch ----------------
extern "C" void kernel_launch(void* const* d_in, const int* in_sizes, int n_in,
                              void* d_out, int out_size, void* d_ws, size_t ws_size,
                              hipStream_t stream) {
  const float* x     = (const float*)d_in[0];
  const float* Wqkv  = (const float*)d_in[1];
  const float* qs    = (const float*)d_in[2];
  const float* ks    = (const float*)d_in[3];
  const float* Wproj = (const float*)d_in[4];
  const float* bproj = (const float*)d_in[5];
  float* out = (float*)d_out;

  char* ws = (char*)d_ws;
  ushort_t* xb     = (ushort_t*)(ws);                                  // 8 MB
  ushort_t* WqkvT  = (ushort_t*)(ws + (size_t)(8u << 20));             // 6 MB
  ushort_t* WprojT = (ushort_t*)(ws + (size_t)(14u << 20));            // 2 MB
  ushort_t* qkb    = (ushort_t*)(ws + (size_t)(16u << 20));            // 16 MB [4096][2048]
  ushort_t* vtb    = (ushort_t*)(ws + (size_t)(32u << 20));            // 8 MB  [2][1024][2048]
  float*    cosT   = (float*)(ws + (size_t)(40u << 20));               // 256 KB
  float*    sinT   = (float*)(ws + (size_t)(40u << 20) + (256u << 10));// 256 KB
  ushort_t* ob     = (ushort_t*)(ws + (size_t)(41u << 20));            // 8 MB

  conv_bf16<<<4096, 256, 0, stream>>>(x, xb, M_ * DIM_ / 4);
  transpose_conv<<<dim3(48, 16), 256, 0, stream>>>(Wqkv, WqkvT, DIM_, N3_);
  transpose_conv<<<dim3(16, 16), 256, 0, stream>>>(Wproj, WprojT, DIM_, DIM_);
  rope_tab<<<256, 256, 0, stream>>>(cosT, sinT);
  gemm_bt<0><<<dim3(24, 32), 256, 0, stream>>>(xb, WqkvT, qkb, vtb, nullptr,
                                               M_, N3_, DIM_, 2048);
  rmsrope<<<4096, 256, 0, stream>>>(qkb, qs, ks, cosT, sinT);
  flash_attn<<<dim3(16, 16, 2), 256, 0, stream>>>(qkb, vtb, ob);
  gemm_bt<1><<<dim3(8, 32), 256, 0, stream>>>(ob, WprojT, out, nullptr, bproj,
                                              M_, DIM_, DIM_, DIM_);
}